// Round 4
// baseline (171.941 us; speedup 1.0000x reference)
//
#include <hip/hip_runtime.h>
#include <math.h>

// R4: TRB=64, 4 waves (nt=4 each), launch_bounds(256,2) for 256-VGPR headroom.
// All weight A-fragments load as batched bursts into named register arrays.
// Wk/Wv hoisted into registers for the whole agent loop; Wsa[n+1] + staging
// prefetched one iteration ahead. 2 barriers/iteration.

typedef __attribute__((ext_vector_type(8))) short bf16x8;
typedef __attribute__((ext_vector_type(4))) float f32x4;

#define TRB 64
#define PITCH 136

__device__ __forceinline__ float lrelu(float x){ return x > 0.f ? x : 0.01f * x; }

__device__ __forceinline__ unsigned short f2bf(float x){
    union { float f; unsigned u; } c; c.f = x;
    unsigned u = c.u; u += 0x7fffu + ((u >> 16) & 1u);
    return (unsigned short)(u >> 16);
}
__device__ __forceinline__ ushort4 pack4(float4 v){
    ushort4 p; p.x = f2bf(v.x); p.y = f2bf(v.y); p.z = f2bf(v.z); p.w = f2bf(v.w);
    return p;
}

__device__ __forceinline__ bf16x8 ldA(const unsigned short* __restrict__ WT, int K,
                                      int m0, int kc, int lane){
    return *(const bf16x8*)(WT + (size_t)(m0 + (lane & 15)) * K + kc * 32 + (lane >> 4) * 8);
}
__device__ __forceinline__ bf16x8 ldB(const unsigned short* L, int n0, int kc, int lane){
    return *(const bf16x8*)(L + (n0 + (lane & 15)) * PITCH + kc * 32 + (lane >> 4) * 8);
}

// batch-load a 32xK W^T fragment block into registers
template<int NKC>
__device__ __forceinline__ void ldW(const unsigned short* __restrict__ WT, int K, int M0,
                                    int lane, bf16x8 F[2][NKC]){
#pragma unroll
    for (int mt = 0; mt < 2; ++mt)
#pragma unroll
        for (int kc = 0; kc < NKC; ++kc)
            F[mt][kc] = ldA(WT, K, M0 + mt * 16, kc, lane);
}

// acc += F(regs) x B(LDS), 2 M-tiles x 4 N-tiles
template<int NKC>
__device__ __forceinline__ void mmR(const bf16x8 F[2][NKC], const unsigned short* Ls,
                                    int lane, f32x4 acc[2][4]){
#pragma unroll
    for (int kc = 0; kc < NKC; ++kc) {
        bf16x8 b[4];
#pragma unroll
        for (int nt = 0; nt < 4; ++nt) b[nt] = ldB(Ls, nt * 16, kc, lane);
#pragma unroll
        for (int mt = 0; mt < 2; ++mt)
#pragma unroll
            for (int nt = 0; nt < 4; ++nt)
                acc[mt][nt] = __builtin_amdgcn_mfma_f32_16x16x32_bf16(F[mt][kc], b[nt], acc[mt][nt], 0, 0, 0);
    }
}

// acc += W^T(global, batch-loaded) x B(LDS)
template<int NKC>
__device__ __forceinline__ void mmG(const unsigned short* __restrict__ WT, int K, int M0,
                                    const unsigned short* Ls, int lane, f32x4 acc[2][4]){
    bf16x8 F[2][NKC];
    ldW<NKC>(WT, K, M0, lane, F);
    mmR<NKC>(F, Ls, lane, acc);
}

// store D-layout acc (+bias, optional lrelu) as bf16 B-layout tile
template<bool ACT>
__device__ __forceinline__ void stD(unsigned short* buf, const f32x4 acc[2][4],
                                    const float* __restrict__ bias, int M0,
                                    int l15, int l4){
#pragma unroll
    for (int mt = 0; mt < 2; ++mt) {
        float4 bb = *(const float4*)(bias + M0 + mt * 16 + l4 * 4);
#pragma unroll
        for (int nt = 0; nt < 4; ++nt) {
            float4 v;
            v.x = acc[mt][nt][0] + bb.x; v.y = acc[mt][nt][1] + bb.y;
            v.z = acc[mt][nt][2] + bb.z; v.w = acc[mt][nt][3] + bb.w;
            if (ACT) { v.x = lrelu(v.x); v.y = lrelu(v.y); v.z = lrelu(v.z); v.w = lrelu(v.w); }
            *(ushort4*)(buf + (nt * 16 + l15) * PITCH + M0 + mt * 16 + l4 * 4) = pack4(v);
        }
    }
}

// staging: load sa-slice for agent n into regs (bf16-packed); n=-1 => s_i
__device__ __forceinline__ void ld_sa(const float* __restrict__ s, const float* __restrict__ a,
                                      int row0, int n, int t, ushort4 sr[6], ushort4 ar[2]){
#pragma unroll
    for (int i = 0; i < 6; ++i) {
        int idx = t + 256 * i; int r = idx / 24, c4 = idx % 24;
        sr[i] = pack4(*(const float4*)(s + (size_t)(row0 + r) * 768 + 96 + 96 * n + c4 * 4));
    }
#pragma unroll
    for (int i = 0; i < 2; ++i) {
        int idx = t + 256 * i; int r = idx >> 3, c4 = idx & 7;
        ar[i] = pack4(*(const float4*)(a + (size_t)(row0 + r) * 256 + 32 + 32 * n + c4 * 4));
    }
}
__device__ __forceinline__ void st_sa(unsigned short* buf, int t,
                                      const ushort4 sr[6], const ushort4 ar[2]){
#pragma unroll
    for (int i = 0; i < 6; ++i) {
        int idx = t + 256 * i; int r = idx / 24, c4 = idx % 24;
        *(ushort4*)(buf + r * PITCH + c4 * 4) = sr[i];
    }
#pragma unroll
    for (int i = 0; i < 2; ++i) {
        int idx = t + 256 * i; int r = idx >> 3, c4 = idx & 7;
        *(ushort4*)(buf + r * PITCH + 96 + c4 * 4) = ar[i];
    }
}

// ---- weight prep: fp32 W[in][out] -> bf16 W^T[out][in] packed in d_ws ----
__global__ void wprep(const float* __restrict__ Ws, const float* __restrict__ Wsa,
                      const float* __restrict__ Wq_, const float* __restrict__ Wk_,
                      const float* __restrict__ Wv_, const float* __restrict__ Wo_,
                      const float* __restrict__ W1, const float* __restrict__ W2,
                      unsigned short* __restrict__ o)
{
    int id = blockIdx.x * 256 + threadIdx.x;
    if (id >= 229376) return;
    float v;
    if (id < 12288)        { int q = id / 96, f = id - q * 96;                         v = Ws[f * 128 + q]; }
    else if (id < 126976)  { int li = id - 12288; int n = li >> 14; int r = li & 16383;
                             int q = r >> 7, f = r & 127;                              v = Wsa[n * 16384 + f * 128 + q]; }
    else if (id < 143360)  { int li = id - 126976; int q = li >> 7, f = li & 127;      v = Wq_[f * 128 + q]; }
    else if (id < 159744)  { int li = id - 143360; int q = li >> 7, f = li & 127;      v = Wk_[f * 128 + q]; }
    else if (id < 176128)  { int li = id - 159744; int q = li >> 7, f = li & 127;      v = Wv_[f * 128 + q]; }
    else if (id < 192512)  { int li = id - 176128; int q = li >> 7, f = li & 127;      v = Wo_[f * 128 + q]; }
    else if (id < 225280)  { int li = id - 192512; int q = li >> 8, f = li & 255;      v = W1[f * 128 + q]; }
    else                   { int li = id - 225280; int q = li >> 7, f = li & 127;      v = W2[f * 32 + q]; }
    o[id] = f2bf(v);
}

#define KV_PHASE(EBP) do {                                                           \
    f32x4 kk[2][4];                                                                  \
    _Pragma("unroll") for (int mt = 0; mt < 2; ++mt)                                 \
    _Pragma("unroll") for (int nt = 0; nt < 4; ++nt)                                 \
        kk[mt][nt] = (f32x4){0.f, 0.f, 0.f, 0.f};                                    \
    mmR<4>(WkF, EBP, lane, kk);                                                      \
    float pr[4], corr[4];                                                            \
    _Pragma("unroll") for (int nt = 0; nt < 4; ++nt) {                               \
        float p = 0.f;                                                               \
        _Pragma("unroll") for (int mt = 0; mt < 2; ++mt)                             \
        _Pragma("unroll") for (int r = 0; r < 4; ++r)                                \
            p = fmaf(q[mt][nt][r], kk[mt][nt][r], p);                                \
        p += __shfl_xor(p, 16); p += __shfl_xor(p, 32);                              \
        float sc = p * 0.17677669529663687f;                                         \
        float mo = m_[nt], mn = fmaxf(mo, sc);                                       \
        pr[nt] = __expf(sc - mn); corr[nt] = __expf(mo - mn);                        \
        l_[nt] = l_[nt] * corr[nt] + pr[nt];                                         \
        m_[nt] = mn;                                                                 \
    }                                                                                \
    f32x4 vv[2][4];                                                                  \
    _Pragma("unroll") for (int mt = 0; mt < 2; ++mt)                                 \
    _Pragma("unroll") for (int nt = 0; nt < 4; ++nt)                                 \
        vv[mt][nt] = (f32x4){0.f, 0.f, 0.f, 0.f};                                    \
    mmR<4>(WvF, EBP, lane, vv);                                                      \
    _Pragma("unroll") for (int mt = 0; mt < 2; ++mt)                                 \
    _Pragma("unroll") for (int nt = 0; nt < 4; ++nt)                                 \
    _Pragma("unroll") for (int r = 0; r < 4; ++r) {                                  \
        float vx = lrelu(vv[mt][nt][r] + ((const float*)&bvf[mt])[r]);               \
        atn[mt][nt][r] = fmaf(atn[mt][nt][r], corr[nt], pr[nt] * vx);                \
    }                                                                                \
} while (0)

__global__ void __launch_bounds__(256, 2)
ac_mfma(const float* __restrict__ s, const float* __restrict__ a,
        const unsigned short* __restrict__ WS,
        const float* __restrict__ b_enc_s, const float* __restrict__ b_enc_sa,
        const float* __restrict__ bv, const float* __restrict__ bo,
        const float* __restrict__ b_fc1, const float* __restrict__ b_fc2,
        float* __restrict__ out_q, float* __restrict__ out_allq)
{
    // 4 x 17408B buffers = 69,632 B -> 2 blocks/CU
    __shared__ __align__(16) unsigned short SMEM[4 * TRB * PITCH];
    unsigned short* bufS = SMEM;                     // staging / attn / h1
    unsigned short* eb0  = SMEM + TRB * PITCH;       // e(even) ; P-overlay
    unsigned short* eb1  = SMEM + 2 * TRB * PITCH;   // e(odd) / ov ; P-overlay
    unsigned short* sENC = SMEM + 3 * TRB * PITCH;   // s_enc ; S-overlay

    const int t = threadIdx.x, lane = t & 63, wid = t >> 6;
    const int l15 = lane & 15, l4 = lane >> 4;
    const int M0 = 32 * wid;
    const int row0 = blockIdx.x * TRB;

    const unsigned short* WencST = WS;
    const unsigned short* WsaT   = WS + 12288;
    const unsigned short* WqT    = WS + 126976;
    const unsigned short* WkT    = WS + 143360;
    const unsigned short* WvT    = WS + 159744;
    const unsigned short* WoT    = WS + 176128;
    const unsigned short* W1T    = WS + 192512;
    const unsigned short* W2T    = WS + 225280;

    // hoisted loop-invariant weights (issue at very top)
    bf16x8 WkF[2][4], WvF[2][4];
    ldW<4>(WkT, 128, M0, lane, WkF);
    ldW<4>(WvT, 128, M0, lane, WvF);

    ushort4 sr[6]; ushort4 ar[2];
    ld_sa(s, a, row0, -1, t, sr, ar);     // s_i
    st_sa(bufS, t, sr, ar);
    __syncthreads();                      // P1

    // ---- s_enc ----
    f32x4 e[2][4];
#pragma unroll
    for (int mt = 0; mt < 2; ++mt)
#pragma unroll
        for (int nt = 0; nt < 4; ++nt) e[mt][nt] = (f32x4){0.f, 0.f, 0.f, 0.f};
    mmG<3>(WencST, 96, M0, bufS, lane, e);
    ld_sa(s, a, row0, 0, t, sr, ar);      // prefetch agent 0
    __syncthreads();                      // P2: bufS reads done
    stD<true>(sENC, e, b_enc_s, M0, l15, l4);
    st_sa(bufS, t, sr, ar);
    bf16x8 WsaF[2][4];
    ldW<4>(WsaT, 128, M0, lane, WsaF);    // Wsa[0]
    __syncthreads();                      // P3: sENC + stage(0) visible

    // ---- Q (register-resident; wave == head) ----
    f32x4 q[2][4];
#pragma unroll
    for (int mt = 0; mt < 2; ++mt)
#pragma unroll
        for (int nt = 0; nt < 4; ++nt) q[mt][nt] = (f32x4){0.f, 0.f, 0.f, 0.f};
    mmG<4>(WqT, 128, M0, sENC, lane, q);

    float4 bvf[2];
#pragma unroll
    for (int mt = 0; mt < 2; ++mt) bvf[mt] = *(const float4*)(bv + M0 + mt * 16 + l4 * 4);

    f32x4 atn[2][4];
#pragma unroll
    for (int mt = 0; mt < 2; ++mt)
#pragma unroll
        for (int nt = 0; nt < 4; ++nt) atn[mt][nt] = (f32x4){0.f, 0.f, 0.f, 0.f};
    float m_[4] = {-INFINITY, -INFINITY, -INFINITY, -INFINITY};
    float l_[4] = {0.f, 0.f, 0.f, 0.f};

    // ---- agent loop: e(n) this interval, K/V(n-1) overlapped ----
#pragma unroll
    for (int n = 0; n < 7; ++n) {
        unsigned short* eb  = (n & 1) ? eb1 : eb0;
        unsigned short* ebp = (n & 1) ? eb0 : eb1;   // e(n-1)
        if (n < 6) ld_sa(s, a, row0, n + 1, t, sr, ar);
#pragma unroll
        for (int mt = 0; mt < 2; ++mt)
#pragma unroll
            for (int nt = 0; nt < 4; ++nt) e[mt][nt] = (f32x4){0.f, 0.f, 0.f, 0.f};
        mmR<4>(WsaF, bufS, lane, e);
        if (n >= 1) KV_PHASE(ebp);
        stD<true>(eb, e, b_enc_sa + n * 128, M0, l15, l4);
        if (n < 6) ldW<4>(WsaT + (n + 1) * 16384, 128, M0, lane, WsaF);
        __syncthreads();                  // A(n): bufS e-reads + ebp KV-reads done
        if (n < 6) st_sa(bufS, t, sr, ar);
        __syncthreads();                  // B(n): e(n) + stage(n+1) visible
    }
    KV_PHASE(eb0);                        // n = 6

    // ---- attn normalize -> bufS ----
#pragma unroll
    for (int mt = 0; mt < 2; ++mt)
#pragma unroll
        for (int nt = 0; nt < 4; ++nt) {
            float inv = 1.f / l_[nt];
            float4 v;
            v.x = atn[mt][nt][0] * inv; v.y = atn[mt][nt][1] * inv;
            v.z = atn[mt][nt][2] * inv; v.w = atn[mt][nt][3] * inv;
            *(ushort4*)(bufS + (nt * 16 + l15) * PITCH + M0 + mt * 16 + l4 * 4) = pack4(v);
        }
    __syncthreads();                      // E1

    // ---- ov = attn @ Wo + bo -> eb1 ----
    f32x4 oa[2][4];
#pragma unroll
    for (int mt = 0; mt < 2; ++mt)
#pragma unroll
        for (int nt = 0; nt < 4; ++nt) oa[mt][nt] = (f32x4){0.f, 0.f, 0.f, 0.f};
    mmG<4>(WoT, 128, M0, bufS, lane, oa);
    stD<false>(eb1, oa, bo, M0, l15, l4);
    __syncthreads();                      // E2: ov visible; bufS Wo-reads done

    // ---- h1 = lrelu([s_enc | ov] @ W1 + b1) -> bufS ----
    f32x4 ha[2][4];
#pragma unroll
    for (int mt = 0; mt < 2; ++mt)
#pragma unroll
        for (int nt = 0; nt < 4; ++nt) ha[mt][nt] = (f32x4){0.f, 0.f, 0.f, 0.f};
    mmG<4>(W1T, 256, M0, sENC, lane, ha);
    mmG<4>(W1T + 128, 256, M0, eb1, lane, ha);
    stD<true>(bufS, ha, b_fc1, M0, l15, l4);
    __syncthreads();                      // E3: h1 visible; sENC/eb1 reads done

    // ---- all_q = h1 @ W2 + b2 : wave wid takes K-chunk wid, partials in LDS ----
    float* P = (float*)(SMEM + TRB * PITCH);       // 32KB overlay on eb0+eb1
    {
        bf16x8 a0 = ldA(W2T, 128, 0, wid, lane);
        bf16x8 a1 = ldA(W2T, 128, 16, wid, lane);
#pragma unroll
        for (int nt = 0; nt < 4; ++nt) {
            bf16x8 b = ldB(bufS, nt * 16, wid, lane);
            f32x4 z = (f32x4){0.f, 0.f, 0.f, 0.f};
            f32x4 c0 = __builtin_amdgcn_mfma_f32_16x16x32_bf16(a0, b, z, 0, 0, 0);
            f32x4 c1 = __builtin_amdgcn_mfma_f32_16x16x32_bf16(a1, b, z, 0, 0, 0);
            *(f32x4*)(P + wid * 2048 + (nt * 16 + l15) * 32 + l4 * 4)      = c0;
            *(f32x4*)(P + wid * 2048 + (nt * 16 + l15) * 32 + 16 + l4 * 4) = c1;
        }
    }
    __syncthreads();                      // E4

    float* S = (float*)(SMEM + 3 * TRB * PITCH);   // stash overlay on sENC
#pragma unroll
    for (int j = 0; j < 8; ++j) {
        int o = t + 256 * j; int row = o >> 5, f = o & 31;
        float v = P[o] + P[2048 + o] + P[4096 + o] + P[6144 + o] + b_fc2[f];
        out_allq[(size_t)(row0 + row) * 32 + f] = v;
        S[row * 33 + f] = v;
    }
    __syncthreads();                      // E5

    // ---- q = all_q[argmax(a[:, :32])] ----
    if (t < TRB) {
        int row = row0 + t;
        const float4* arr = (const float4*)(a + (size_t)row * 256);
        float best = -INFINITY; int bi = 0;
#pragma unroll
        for (int jj = 0; jj < 8; ++jj) {
            float4 v = arr[jj];
            float vv[4] = {v.x, v.y, v.z, v.w};
#pragma unroll
            for (int e2 = 0; e2 < 4; ++e2)
                if (vv[e2] > best) { best = vv[e2]; bi = jj * 4 + e2; }
        }
        out_q[row] = S[t * 33 + bi];
    }
}

extern "C" void kernel_launch(void* const* d_in, const int* in_sizes, int n_in,
                              void* d_out, int out_size, void* d_ws, size_t ws_size,
                              hipStream_t stream)
{
    (void)n_in; (void)out_size; (void)ws_size;
    const float* s        = (const float*)d_in[0];
    const float* a        = (const float*)d_in[1];
    const float* W_enc_s  = (const float*)d_in[2];
    const float* b_enc_s  = (const float*)d_in[3];
    const float* W_enc_sa = (const float*)d_in[4];
    const float* b_enc_sa = (const float*)d_in[5];
    const float* Wq       = (const float*)d_in[6];
    const float* Wk       = (const float*)d_in[7];
    const float* Wv       = (const float*)d_in[8];
    const float* bv       = (const float*)d_in[9];
    const float* Wo       = (const float*)d_in[10];
    const float* bo       = (const float*)d_in[11];
    const float* W_fc1    = (const float*)d_in[12];
    const float* b_fc1    = (const float*)d_in[13];
    const float* W_fc2    = (const float*)d_in[14];
    const float* b_fc2    = (const float*)d_in[15];

    int B = in_sizes[0] / 768;
    float* out_q    = (float*)d_out;
    float* out_allq = out_q + B;
    unsigned short* WS = (unsigned short*)d_ws;

    wprep<<<dim3(896), dim3(256), 0, stream>>>(W_enc_s, W_enc_sa, Wq, Wk, Wv, Wo,
                                               W_fc1, W_fc2, WS);
    ac_mfma<<<dim3(B / TRB), dim3(256), 0, stream>>>(s, a, WS, b_enc_s, b_enc_sa,
                                                     bv, bo, b_fc1, b_fc2,
                                                     out_q, out_allq);
}